// Round 4
// baseline (1444.004 us; speedup 1.0000x reference)
//
#include <hip/hip_runtime.h>
#include <hip/hip_bf16.h>

#define NN 10000
#define EE 120000
#define E_PAD 120064   // 938 * 128
#define NTILES 938     // E_PAD / 128

typedef __bf16 bf16_t;
typedef __bf16 bf16x8 __attribute__((ext_vector_type(8)));
typedef float f32x4 __attribute__((ext_vector_type(4)));

static __device__ __forceinline__ int clampi(int v) {
    return v < 0 ? 0 : (v >= NN ? NN - 1 : v);
}

// ---- float dtype detection -------------------------------------------------
// edge_attr ~ uniform[0,1): as bf16, every 16-bit word has sign bit 0.
// As fp32, the low half-words are random mantissa bits -> ~50% have bit15 set.
__global__ __launch_bounds__(256) void detect_f32(const unsigned short* __restrict__ ea_raw,
                                                  int* __restrict__ flag) {
    int t = blockIdx.x * 256 + threadIdx.x;   // [0, 8192) words, in-bounds either dtype
    if (ea_raw[t] & 0x8000) atomicOr(flag, 1);
}

// ---- batched convert of all 16 float tensors to canonical fp32 ------------
#define N_FLT 16
struct CvtArgs {
    const void* src[N_FLT];
    float* dst;
    int offs[N_FLT];
    int n[N_FLT];
};

__global__ __launch_bounds__(256) void cvt_all(CvtArgs a, const int* __restrict__ isf32) {
    int tensor = blockIdx.y;
    int i = blockIdx.x * 256 + threadIdx.x;
    if (i >= a.n[tensor]) return;
    float v;
    if (*isf32) v = ((const float*)a.src[tensor])[i];
    else        v = (float)((const bf16_t*)a.src[tensor])[i];
    if (!isfinite(v)) v = 0.f;   // insurance against misdetection
    a.dst[a.offs[tensor] + i] = v;
}

// ---- index dtype handling (int32 vs int64) ---------------------------------
__global__ __launch_bounds__(256) void detect_idx(const int* __restrict__ ei,
                                                  int* __restrict__ flag) {
    int t = blockIdx.x * 256 + threadIdx.x;          // [0, 4096)
    if (ei[2 * t + 1] != 0) atomicOr(flag, 1);       // any nonzero odd word -> int32
}

__global__ __launch_bounds__(256) void repack_idx(const int* __restrict__ ei,
                                                  const int* __restrict__ flag,
                                                  int* __restrict__ s,
                                                  int* __restrict__ d) {
    int e = blockIdx.x * 256 + threadIdx.x;
    if (e >= EE) return;
    if (*flag == 0) {   // int64
        s[e] = clampi(ei[2 * e]);
        d[e] = clampi(ei[2 * (EE + e)]);
    } else {            // int32
        s[e] = clampi(ei[e]);
        d[e] = clampi(ei[EE + e]);
    }
}

__global__ __launch_bounds__(256) void cnt_kernel(const int* __restrict__ dst,
                                                  float* __restrict__ cnt) {
    int e = blockIdx.x * 256 + threadIdx.x;
    if (e < EE) atomicAdd(&cnt[dst[e]], 1.0f);
}

// ---- prep kernels (canonical fp32 in) --------------------------------------

__global__ __launch_bounds__(256) void transpose_bt(const float* __restrict__ B,
                                                    bf16_t* __restrict__ Bt, int K, int N) {
    int idx = blockIdx.x * 256 + threadIdx.x;   // idx = n*K + k
    if (idx >= K * N) return;
    int n = idx / K, k = idx - n * K;
    Bt[idx] = (bf16_t)B[k * N + n];
}

// h0 = x @ fc1_w + fc1_b   (N x 32, fp32)
__global__ __launch_bounds__(256) void h0_kernel(const float* __restrict__ x,
                                                 const float* __restrict__ w,
                                                 const float* __restrict__ b,
                                                 float* __restrict__ h) {
    int gid = blockIdx.x * 256 + threadIdx.x;   // n*32 + o
    int n = gid >> 5, o = gid & 31;
    float acc = b[o];
#pragma unroll
    for (int j = 0; j < 6; ++j) acc += x[n * 6 + j] * w[j * 32 + o];
    h[gid] = acc;
}

// h1_c[r,:] = relu(edge_attr[e0+r,:] @ k1_w + k1_b)  (chunk-local rows, bf16 out)
__global__ __launch_bounds__(256) void h1_chunk(const float* __restrict__ ea,
                                                const float* __restrict__ k1w,
                                                const float* __restrict__ k1b,
                                                bf16_t* __restrict__ h1, int e0) {
    __shared__ float wk[6 * 128];
    __shared__ float bk[128];
    for (int i = threadIdx.x; i < 768; i += 256) wk[i] = k1w[i];
    if (threadIdx.x < 128) bk[threadIdx.x] = k1b[threadIdx.x];
    __syncthreads();
    int gid = blockIdx.x * 256 + threadIdx.x;   // r*128 + o
    int r = gid >> 7, o = gid & 127;
    int e = e0 + r;
    if (e >= EE) { h1[gid] = (bf16_t)0.f; return; }
    float acc = bk[o];
#pragma unroll
    for (int j = 0; j < 6; ++j) acc += ea[e * 6 + j] * wk[j * 128 + o];
    h1[gid] = (bf16_t)fmaxf(acc, 0.f);
}

// ---- MFMA GEMM:  C[M,Nd] = act(A[M,K] @ Bt[Nd,K]^T + bias) ----------------
// Register->LDS staging (known-safe structure).
__global__ __launch_bounds__(256) void gemm_bt(const bf16_t* __restrict__ A,
                                               const bf16_t* __restrict__ Bt,
                                               const float* __restrict__ bias,
                                               bf16_t* __restrict__ C,
                                               int K, int Nd, int relu) {
    __shared__ bf16_t As[128 * 32];
    __shared__ bf16_t Bs[128 * 32];
    const int t = threadIdx.x;
    const int lane = t & 63;
    const int wave = t >> 6;
    const int wm = wave >> 1, wn = wave & 1;
    const long m0 = (long)blockIdx.x * 128;
    const int n0 = blockIdx.y * 128;

    f32x4 acc[4][4];
#pragma unroll
    for (int i = 0; i < 4; ++i)
#pragma unroll
        for (int j = 0; j < 4; ++j) acc[i][j] = f32x4{0.f, 0.f, 0.f, 0.f};

    const int ar = t >> 2;         // 0..63 (row within half-tile)
    const int ac = (t & 3) * 8;    // k element offset 0/8/16/24
    const bf16_t* gA0 = A + (m0 + ar) * (long)K + ac;
    const bf16_t* gA1 = A + (m0 + 64 + ar) * (long)K + ac;
    const bf16_t* gB0 = Bt + (long)(n0 + ar) * K + ac;
    const bf16_t* gB1 = Bt + (long)(n0 + 64 + ar) * K + ac;
    bf16_t* lA0 = &As[t * 8];
    bf16_t* lA1 = &As[2048 + t * 8];
    bf16_t* lB0 = &Bs[t * 8];
    bf16_t* lB1 = &Bs[2048 + t * 8];

    const int mrow = wm * 64 + (lane & 15);
    const int nrow = wn * 64 + (lane & 15);
    const int koff = (lane >> 4) * 8;

    for (int k0 = 0; k0 < K; k0 += 32) {
        bf16x8 va0 = *(const bf16x8*)(gA0 + k0);
        bf16x8 va1 = *(const bf16x8*)(gA1 + k0);
        bf16x8 vb0 = *(const bf16x8*)(gB0 + k0);
        bf16x8 vb1 = *(const bf16x8*)(gB1 + k0);
        __syncthreads();
        *(bf16x8*)lA0 = va0;
        *(bf16x8*)lA1 = va1;
        *(bf16x8*)lB0 = vb0;
        *(bf16x8*)lB1 = vb1;
        __syncthreads();

        bf16x8 af[4], bfr[4];
#pragma unroll
        for (int i = 0; i < 4; ++i) af[i] = *(const bf16x8*)&As[(mrow + i * 16) * 32 + koff];
#pragma unroll
        for (int j = 0; j < 4; ++j) bfr[j] = *(const bf16x8*)&Bs[(nrow + j * 16) * 32 + koff];
#pragma unroll
        for (int i = 0; i < 4; ++i)
#pragma unroll
            for (int j = 0; j < 4; ++j)
                acc[i][j] = __builtin_amdgcn_mfma_f32_16x16x32_bf16(af[i], bfr[j], acc[i][j], 0, 0, 0);
    }

    // C/D layout: col = lane&15, row = (lane>>4)*4 + reg   [verified m89]
    const int rbase = (lane >> 4) * 4;
    const int cidx = lane & 15;
#pragma unroll
    for (int i = 0; i < 4; ++i) {
#pragma unroll
        for (int j = 0; j < 4; ++j) {
            int col = n0 + wn * 64 + j * 16 + cidx;
            float bv = bias[col];
#pragma unroll
            for (int r = 0; r < 4; ++r) {
                long row = m0 + wm * 64 + i * 16 + rbase + r;
                float v = acc[i][j][r] + bv;
                if (relu) v = fmaxf(v, 0.f);
                C[row * Nd + col] = (bf16_t)v;
            }
        }
    }
}

// ---- per-layer: msg = h[src] @ w_e, scatter-add to aggr[dst] ---------------
__global__ __launch_bounds__(256) void matvec_scatter(const float* __restrict__ h,
                                                      const bf16_t* __restrict__ we,
                                                      const int* __restrict__ src,
                                                      const int* __restrict__ dst,
                                                      float* __restrict__ aggr,
                                                      int e0, int e1) {
    int e = e0 + blockIdx.x * 256 + threadIdx.x;
    if (e >= e1) return;
    int s = src[e], d = dst[e];
    float hr[32];
    const float4* hp = (const float4*)(h + (size_t)s * 32);
#pragma unroll
    for (int i = 0; i < 8; ++i) {
        float4 v = hp[i];
        hr[i * 4] = v.x; hr[i * 4 + 1] = v.y; hr[i * 4 + 2] = v.z; hr[i * 4 + 3] = v.w;
    }
    float msg[32];
#pragma unroll
    for (int o = 0; o < 32; ++o) msg[o] = 0.f;
    const bf16x8* wp = (const bf16x8*)(we + (size_t)(e - e0) * 1024);
#pragma unroll 8
    for (int i = 0; i < 32; ++i) {
        float hi = hr[i];
#pragma unroll
        for (int c = 0; c < 4; ++c) {
            bf16x8 wv = wp[i * 4 + c];
#pragma unroll
            for (int j = 0; j < 8; ++j) msg[c * 8 + j] += hi * (float)wv[j];
        }
    }
    float* ap = aggr + (size_t)d * 32;
#pragma unroll
    for (int o = 0; o < 32; ++o) atomicAdd(&ap[o], msg[o]);
}

// h_out = act(aggr/denom + h_in @ root_w + conv_b)
__global__ __launch_bounds__(256) void node_update(const float* __restrict__ hin,
                                                   const float* __restrict__ aggr,
                                                   const float* __restrict__ cnt,
                                                   const float* __restrict__ rw,
                                                   const float* __restrict__ cb,
                                                   float* __restrict__ hout, int relu) {
    __shared__ float rws[32 * 32];
    for (int i = threadIdx.x; i < 1024; i += 256) rws[i] = rw[i];
    __syncthreads();
    int gid = blockIdx.x * 256 + threadIdx.x;   // n*32 + o
    int n = gid >> 5, o = gid & 31;
    float den = fmaxf(cnt[n], 1.f);
    float acc = aggr[gid] / den + cb[o];
    const float* hrow = hin + (size_t)n * 32;
#pragma unroll
    for (int j = 0; j < 32; ++j) acc += hrow[j] * rws[j * 32 + o];
    if (relu) acc = fmaxf(acc, 0.f);
    hout[gid] = acc;
}

// out = relu(h @ fc2 + b2) @ fc3 + b3 ; one wave per node; out dtype per flag
__global__ __launch_bounds__(256) void head_kernel(const float* __restrict__ h,
                                                   const float* __restrict__ w2,
                                                   const float* __restrict__ b2,
                                                   const float* __restrict__ w3,
                                                   const float* __restrict__ b3,
                                                   void* __restrict__ out,
                                                   const int* __restrict__ isf32) {
    int wave = threadIdx.x >> 6, lane = threadIdx.x & 63;
    int n = blockIdx.x * 4 + wave;
    if (n >= NN) return;
    const float* hrow = h + (size_t)n * 32;
    float hr[32];
#pragma unroll
    for (int j = 0; j < 32; ++j) hr[j] = hrow[j];
    int o0 = lane * 2, o1 = lane * 2 + 1;
    float v0 = b2[o0], v1 = b2[o1];
#pragma unroll
    for (int j = 0; j < 32; ++j) {
        float hj = hr[j];
        v0 += hj * w2[j * 128 + o0];
        v1 += hj * w2[j * 128 + o1];
    }
    float y = fmaxf(v0, 0.f) * w3[o0] + fmaxf(v1, 0.f) * w3[o1];
#pragma unroll
    for (int m = 1; m < 64; m <<= 1) y += __shfl_xor(y, m, 64);
    if (lane == 0) {
        float r = y + b3[0];
        if (*isf32) ((float*)out)[n] = r;
        else        ((bf16_t*)out)[n] = (bf16_t)r;
    }
}

// ---------------------------------------------------------------------------

extern "C" void kernel_launch(void* const* d_in, const int* in_sizes, int n_in,
                              void* d_out, int out_size, void* d_ws, size_t ws_size,
                              hipStream_t stream) {
    const int* ei = (const int*)d_in[1];

    char* ws = (char*)d_ws;
    size_t off = 0;
    auto alloc = [&](size_t bytes) {
        char* p = ws + off;
        off += (bytes + 255) & ~(size_t)255;
        return (void*)p;
    };
    float*  h_a   = (float*)alloc((size_t)NN * 32 * 4);
    float*  h_b   = (float*)alloc((size_t)NN * 32 * 4);
    float*  aggr  = (float*)alloc((size_t)NN * 32 * 4);
    float*  cnt   = (float*)alloc((size_t)NN * 4);
    int*    f32fl = (int*)alloc(256);
    int*    idxfl = (int*)alloc(256);
    int*    srcb  = (int*)alloc((size_t)EE * 4);
    int*    dstb  = (int*)alloc((size_t)EE * 4);
    bf16_t* k2t   = (bf16_t*)alloc(256 * 128 * 2);
    bf16_t* k3t   = (bf16_t*)alloc(1024 * 256 * 2);

    // canonical fp32 copies of the 16 float tensors
    static const int fidx[N_FLT] = {0, 2, 3, 4, 5, 6, 7, 8, 9, 10, 11, 12, 13, 14, 15, 16};
    static const int fn[N_FLT]   = {NN * 6, EE * 6, 192, 32, 768, 128, 32768, 256,
                                    262144, 1024, 1024, 32, 4096, 128, 128, 1};
    int foffs[N_FLT];
    int tot = 0;
    for (int i = 0; i < N_FLT; ++i) { foffs[i] = tot; tot += fn[i]; }
    float* canon = (float*)alloc((size_t)tot * 4);
    const float* c_x    = canon + foffs[0];
    const float* c_ea   = canon + foffs[1];
    const float* c_fc1w = canon + foffs[2];
    const float* c_fc1b = canon + foffs[3];
    const float* c_k1w  = canon + foffs[4];
    const float* c_k1b  = canon + foffs[5];
    const float* c_k2w  = canon + foffs[6];
    const float* c_k2b  = canon + foffs[7];
    const float* c_k3w  = canon + foffs[8];
    const float* c_k3b  = canon + foffs[9];
    const float* c_rw   = canon + foffs[10];
    const float* c_cb   = canon + foffs[11];
    const float* c_fc2w = canon + foffs[12];
    const float* c_fc2b = canon + foffs[13];
    const float* c_fc3w = canon + foffs[14];
    const float* c_fc3b = canon + foffs[15];
    size_t fixed_end = off;

    // Path selection on ws_size (constant per harness instance -> graph-safe).
    const size_t per_tile = (size_t)128 * 128 * 2 + 128 * 256 * 2 + 128 * 1024 * 2;
    const int T_full = 64;
    size_t full_need = fixed_end
                     + (((size_t)T_full * 128 * 128 * 2 + 255) & ~(size_t)255)
                     + (((size_t)T_full * 128 * 256 * 2 + 255) & ~(size_t)255)
                     + (size_t)E_PAD * 1024 * 2;
    bool full = ws_size >= full_need;
    int T;
    if (full) {
        T = T_full;
    } else {
        size_t avail = ws_size > fixed_end + 4096 ? ws_size - fixed_end - 4096 : per_tile;
        long t = (long)(avail / per_tile);
        if (t > NTILES) t = NTILES;
        if (t < 1) t = 1;
        T = (int)t;
    }
    bf16_t* h1_c = (bf16_t*)alloc((size_t)T * 128 * 128 * 2);
    bf16_t* h2_c = (bf16_t*)alloc((size_t)T * 128 * 256 * 2);
    bf16_t* w_e  = (bf16_t*)alloc(full ? (size_t)E_PAD * 1024 * 2
                                       : (size_t)T * 128 * 1024 * 2);

    hipMemsetAsync(cnt, 0, (size_t)NN * 4, stream);
    hipMemsetAsync(f32fl, 0, 256, stream);
    hipMemsetAsync(idxfl, 0, 256, stream);

    detect_f32<<<32, 256, 0, stream>>>((const unsigned short*)d_in[2], f32fl);

    CvtArgs ca;
    for (int i = 0; i < N_FLT; ++i) {
        ca.src[i] = d_in[fidx[i]];
        ca.offs[i] = foffs[i];
        ca.n[i] = fn[i];
    }
    ca.dst = canon;
    {
        dim3 g((EE * 6 + 255) / 256, N_FLT);
        cvt_all<<<g, 256, 0, stream>>>(ca, f32fl);
    }

    detect_idx<<<16, 256, 0, stream>>>(ei, idxfl);
    repack_idx<<<(EE + 255) / 256, 256, 0, stream>>>(ei, idxfl, srcb, dstb);
    cnt_kernel<<<(EE + 255) / 256, 256, 0, stream>>>(dstb, cnt);
    transpose_bt<<<(128 * 256 + 255) / 256, 256, 0, stream>>>(c_k2w, k2t, 128, 256);
    transpose_bt<<<(256 * 1024 + 255) / 256, 256, 0, stream>>>(c_k3w, k3t, 256, 1024);
    h0_kernel<<<NN * 32 / 256, 256, 0, stream>>>(c_x, c_fc1w, c_fc1b, h_a);

    auto prep_chunk = [&](int tile0, int tiles, bf16_t* we_dst) {
        int rows = tiles * 128;
        h1_chunk<<<rows * 128 / 256, 256, 0, stream>>>(c_ea, c_k1w, c_k1b, h1_c, tile0 * 128);
        dim3 g2(tiles, 2);
        gemm_bt<<<g2, 256, 0, stream>>>(h1_c, k2t, c_k2b, h2_c, 128, 256, 1);
        dim3 g3(tiles, 8);
        gemm_bt<<<g3, 256, 0, stream>>>(h2_c, k3t, c_k3b, we_dst, 256, 1024, 0);
    };

    float* hc = h_a;
    float* hn = h_b;
    if (full) {
        for (int t0 = 0; t0 < NTILES; t0 += T) {
            int tl = (t0 + T <= NTILES) ? T : (NTILES - t0);
            prep_chunk(t0, tl, w_e + (size_t)t0 * 128 * 1024);
        }
        for (int d = 0; d < 4; ++d) {
            hipMemsetAsync(aggr, 0, (size_t)NN * 32 * 4, stream);
            matvec_scatter<<<(EE + 255) / 256, 256, 0, stream>>>(hc, w_e, srcb, dstb, aggr, 0, EE);
            node_update<<<NN * 32 / 256, 256, 0, stream>>>(hc, aggr, cnt, c_rw, c_cb, hn,
                                                           (d < 3) ? 1 : 0);
            float* tmp = hc; hc = hn; hn = tmp;
        }
    } else {
        for (int d = 0; d < 4; ++d) {
            hipMemsetAsync(aggr, 0, (size_t)NN * 32 * 4, stream);
            for (int t0 = 0; t0 < NTILES; t0 += T) {
                int tl = (t0 + T <= NTILES) ? T : (NTILES - t0);
                prep_chunk(t0, tl, w_e);
                int e0 = t0 * 128;
                int e1 = e0 + tl * 128; if (e1 > EE) e1 = EE;
                if (e1 > e0)
                    matvec_scatter<<<(e1 - e0 + 255) / 256, 256, 0, stream>>>(hc, w_e, srcb, dstb, aggr, e0, e1);
            }
            node_update<<<NN * 32 / 256, 256, 0, stream>>>(hc, aggr, cnt, c_rw, c_cb, hn,
                                                           (d < 3) ? 1 : 0);
            float* tmp = hc; hc = hn; hn = tmp;
        }
    }

    head_kernel<<<(NN + 3) / 4, 256, 0, stream>>>(hc, c_fc2w, c_fc2b, c_fc3w, c_fc3b,
                                                  d_out, f32fl);
}

// Round 5
// 994.908 us; speedup vs baseline: 1.4514x; 1.4514x over previous
//
#include <hip/hip_runtime.h>
#include <hip/hip_bf16.h>

#define NN 10000
#define EE 120000
#define E_PAD 120064   // 938 * 128
#define NTILES 938     // E_PAD / 128

typedef __bf16 bf16_t;
typedef __bf16 bf16x8 __attribute__((ext_vector_type(8)));
typedef float f32x4 __attribute__((ext_vector_type(4)));

static __device__ __forceinline__ int clampi(int v) {
    return v < 0 ? 0 : (v >= NN ? NN - 1 : v);
}

// ---- float dtype detection -------------------------------------------------
__global__ __launch_bounds__(256) void detect_f32(const unsigned short* __restrict__ ea_raw,
                                                  int* __restrict__ flag) {
    int t = blockIdx.x * 256 + threadIdx.x;   // [0, 8192) words, in-bounds either dtype
    if (ea_raw[t] & 0x8000) atomicOr(flag, 1);
}

// ---- batched convert of all 16 float tensors to canonical fp32 ------------
#define N_FLT 16
struct CvtArgs {
    const void* src[N_FLT];
    float* dst;
    int offs[N_FLT];
    int n[N_FLT];
};

__global__ __launch_bounds__(256) void cvt_all(CvtArgs a, const int* __restrict__ isf32) {
    int tensor = blockIdx.y;
    int i = blockIdx.x * 256 + threadIdx.x;
    if (i >= a.n[tensor]) return;
    float v;
    if (*isf32) v = ((const float*)a.src[tensor])[i];
    else        v = (float)((const bf16_t*)a.src[tensor])[i];
    if (!isfinite(v)) v = 0.f;   // insurance against misdetection
    a.dst[a.offs[tensor] + i] = v;
}

// ---- index dtype handling (int32 vs int64) ---------------------------------
__global__ __launch_bounds__(256) void detect_idx(const int* __restrict__ ei,
                                                  int* __restrict__ flag) {
    int t = blockIdx.x * 256 + threadIdx.x;          // [0, 4096)
    if (ei[2 * t + 1] != 0) atomicOr(flag, 1);       // any nonzero odd word -> int32
}

__global__ __launch_bounds__(256) void repack_idx(const int* __restrict__ ei,
                                                  const int* __restrict__ flag,
                                                  int* __restrict__ s,
                                                  int* __restrict__ d) {
    int e = blockIdx.x * 256 + threadIdx.x;
    if (e >= EE) return;
    if (*flag == 0) {   // int64
        s[e] = clampi(ei[2 * e]);
        d[e] = clampi(ei[2 * (EE + e)]);
    } else {            // int32
        s[e] = clampi(ei[e]);
        d[e] = clampi(ei[EE + e]);
    }
}

__global__ __launch_bounds__(256) void cnt_kernel(const int* __restrict__ dst,
                                                  float* __restrict__ cnt) {
    int e = blockIdx.x * 256 + threadIdx.x;
    if (e < EE) atomicAdd(&cnt[dst[e]], 1.0f);
}

// ---- prep kernels (canonical fp32 in) --------------------------------------

__global__ __launch_bounds__(256) void transpose_bt(const float* __restrict__ B,
                                                    bf16_t* __restrict__ Bt, int K, int N) {
    int idx = blockIdx.x * 256 + threadIdx.x;   // idx = n*K + k
    if (idx >= K * N) return;
    int n = idx / K, k = idx - n * K;
    Bt[idx] = (bf16_t)B[k * N + n];
}

// h0 = x @ fc1_w + fc1_b   (N x 32, fp32)
__global__ __launch_bounds__(256) void h0_kernel(const float* __restrict__ x,
                                                 const float* __restrict__ w,
                                                 const float* __restrict__ b,
                                                 float* __restrict__ h) {
    int gid = blockIdx.x * 256 + threadIdx.x;   // n*32 + o
    int n = gid >> 5, o = gid & 31;
    float acc = b[o];
#pragma unroll
    for (int j = 0; j < 6; ++j) acc += x[n * 6 + j] * w[j * 32 + o];
    h[gid] = acc;
}

// h1_c[r,:] = relu(edge_attr[e0+r,:] @ k1_w + k1_b)  (chunk-local rows, bf16 out)
__global__ __launch_bounds__(256) void h1_chunk(const float* __restrict__ ea,
                                                const float* __restrict__ k1w,
                                                const float* __restrict__ k1b,
                                                bf16_t* __restrict__ h1, int e0) {
    __shared__ float wk[6 * 128];
    __shared__ float bk[128];
    for (int i = threadIdx.x; i < 768; i += 256) wk[i] = k1w[i];
    if (threadIdx.x < 128) bk[threadIdx.x] = k1b[threadIdx.x];
    __syncthreads();
    int gid = blockIdx.x * 256 + threadIdx.x;   // r*128 + o
    int r = gid >> 7, o = gid & 127;
    int e = e0 + r;
    if (e >= EE) { h1[gid] = (bf16_t)0.f; return; }
    float acc = bk[o];
#pragma unroll
    for (int j = 0; j < 6; ++j) acc += ea[e * 6 + j] * wk[j * 128 + o];
    h1[gid] = (bf16_t)fmaxf(acc, 0.f);
}

// ---- MFMA GEMM:  C[M,Nd] = act(A[M,K] @ Bt[Nd,K]^T + bias) ----------------
__global__ __launch_bounds__(256) void gemm_bt(const bf16_t* __restrict__ A,
                                               const bf16_t* __restrict__ Bt,
                                               const float* __restrict__ bias,
                                               bf16_t* __restrict__ C,
                                               int K, int Nd, int relu) {
    __shared__ bf16_t As[128 * 32];
    __shared__ bf16_t Bs[128 * 32];
    const int t = threadIdx.x;
    const int lane = t & 63;
    const int wave = t >> 6;
    const int wm = wave >> 1, wn = wave & 1;
    const long m0 = (long)blockIdx.x * 128;
    const int n0 = blockIdx.y * 128;

    f32x4 acc[4][4];
#pragma unroll
    for (int i = 0; i < 4; ++i)
#pragma unroll
        for (int j = 0; j < 4; ++j) acc[i][j] = f32x4{0.f, 0.f, 0.f, 0.f};

    const int ar = t >> 2;
    const int ac = (t & 3) * 8;
    const bf16_t* gA0 = A + (m0 + ar) * (long)K + ac;
    const bf16_t* gA1 = A + (m0 + 64 + ar) * (long)K + ac;
    const bf16_t* gB0 = Bt + (long)(n0 + ar) * K + ac;
    const bf16_t* gB1 = Bt + (long)(n0 + 64 + ar) * K + ac;
    bf16_t* lA0 = &As[t * 8];
    bf16_t* lA1 = &As[2048 + t * 8];
    bf16_t* lB0 = &Bs[t * 8];
    bf16_t* lB1 = &Bs[2048 + t * 8];

    const int mrow = wm * 64 + (lane & 15);
    const int nrow = wn * 64 + (lane & 15);
    const int koff = (lane >> 4) * 8;

    for (int k0 = 0; k0 < K; k0 += 32) {
        bf16x8 va0 = *(const bf16x8*)(gA0 + k0);
        bf16x8 va1 = *(const bf16x8*)(gA1 + k0);
        bf16x8 vb0 = *(const bf16x8*)(gB0 + k0);
        bf16x8 vb1 = *(const bf16x8*)(gB1 + k0);
        __syncthreads();
        *(bf16x8*)lA0 = va0;
        *(bf16x8*)lA1 = va1;
        *(bf16x8*)lB0 = vb0;
        *(bf16x8*)lB1 = vb1;
        __syncthreads();

        bf16x8 af[4], bfr[4];
#pragma unroll
        for (int i = 0; i < 4; ++i) af[i] = *(const bf16x8*)&As[(mrow + i * 16) * 32 + koff];
#pragma unroll
        for (int j = 0; j < 4; ++j) bfr[j] = *(const bf16x8*)&Bs[(nrow + j * 16) * 32 + koff];
#pragma unroll
        for (int i = 0; i < 4; ++i)
#pragma unroll
            for (int j = 0; j < 4; ++j)
                acc[i][j] = __builtin_amdgcn_mfma_f32_16x16x32_bf16(af[i], bfr[j], acc[i][j], 0, 0, 0);
    }

    const int rbase = (lane >> 4) * 4;
    const int cidx = lane & 15;
#pragma unroll
    for (int i = 0; i < 4; ++i) {
#pragma unroll
        for (int j = 0; j < 4; ++j) {
            int col = n0 + wn * 64 + j * 16 + cidx;
            float bv = bias[col];
#pragma unroll
            for (int r = 0; r < 4; ++r) {
                long row = m0 + wm * 64 + i * 16 + rbase + r;
                float v = acc[i][j][r] + bv;
                if (relu) v = fmaxf(v, 0.f);
                C[row * Nd + col] = (bf16_t)v;
            }
        }
    }
}

// ---- per-layer: msg = h[src] @ w_e, scatter-add to aggr[dst] ---------------
// One 64-lane wave per edge; we rows are chunk-local (row = e - e0).
__global__ __launch_bounds__(256) void matvec_scatter(const float* __restrict__ h,
                                                      const bf16_t* __restrict__ we,
                                                      const int* __restrict__ src,
                                                      const int* __restrict__ dst,
                                                      float* __restrict__ aggr,
                                                      int e0, int e1) {
    int wave = threadIdx.x >> 6;
    int lane = threadIdx.x & 63;
    int e = e0 + blockIdx.x * 4 + wave;
    if (e >= e1) return;
    int s = src[e], d = dst[e];

    const int r  = lane >> 1;
    const int ch = lane & 1;

    float hv = h[(size_t)s * 32 + (lane & 31)];
    float hr = __shfl(hv, r, 64);           // h[s][r]

    const bf16x8* wp = (const bf16x8*)(we + (size_t)(e - e0) * 1024 + lane * 16);
    bf16x8 w0 = wp[0];
    bf16x8 w1 = wp[1];

    float p[16];
#pragma unroll
    for (int j = 0; j < 8; ++j) {
        p[j]     = hr * (float)w0[j];
        p[8 + j] = hr * (float)w1[j];
    }
#pragma unroll
    for (int m = 2; m <= 32; m <<= 1) {
#pragma unroll
        for (int j = 0; j < 16; ++j) p[j] += __shfl_xor(p[j], m, 64);
    }
    if ((lane & 30) == 0) {                 // lanes 0,1,32,33
        int jbase = (lane >> 5) * 8;
        float* ap = aggr + (size_t)d * 32 + ch * 16 + jbase;
#pragma unroll
        for (int j = 0; j < 8; ++j) atomicAdd(&ap[j], p[jbase + j]);
    }
}

// h_out = act(aggr/denom + h_in @ root_w + conv_b)
__global__ __launch_bounds__(256) void node_update(const float* __restrict__ hin,
                                                   const float* __restrict__ aggr,
                                                   const float* __restrict__ cnt,
                                                   const float* __restrict__ rw,
                                                   const float* __restrict__ cb,
                                                   float* __restrict__ hout, int relu) {
    __shared__ float rws[32 * 32];
    for (int i = threadIdx.x; i < 1024; i += 256) rws[i] = rw[i];
    __syncthreads();
    int gid = blockIdx.x * 256 + threadIdx.x;   // n*32 + o
    int n = gid >> 5, o = gid & 31;
    float den = fmaxf(cnt[n], 1.f);
    float acc = aggr[gid] / den + cb[o];
    const float* hrow = hin + (size_t)n * 32;
#pragma unroll
    for (int j = 0; j < 32; ++j) acc += hrow[j] * rws[j * 32 + o];
    if (relu) acc = fmaxf(acc, 0.f);
    hout[gid] = acc;
}

// out = relu(h @ fc2 + b2) @ fc3 + b3 ; one wave per node; out dtype per flag
__global__ __launch_bounds__(256) void head_kernel(const float* __restrict__ h,
                                                   const float* __restrict__ w2,
                                                   const float* __restrict__ b2,
                                                   const float* __restrict__ w3,
                                                   const float* __restrict__ b3,
                                                   void* __restrict__ out,
                                                   const int* __restrict__ isf32) {
    int wave = threadIdx.x >> 6, lane = threadIdx.x & 63;
    int n = blockIdx.x * 4 + wave;
    if (n >= NN) return;
    const float* hrow = h + (size_t)n * 32;
    float hr[32];
#pragma unroll
    for (int j = 0; j < 32; ++j) hr[j] = hrow[j];
    int o0 = lane * 2, o1 = lane * 2 + 1;
    float v0 = b2[o0], v1 = b2[o1];
#pragma unroll
    for (int j = 0; j < 32; ++j) {
        float hj = hr[j];
        v0 += hj * w2[j * 128 + o0];
        v1 += hj * w2[j * 128 + o1];
    }
    float y = fmaxf(v0, 0.f) * w3[o0] + fmaxf(v1, 0.f) * w3[o1];
#pragma unroll
    for (int m = 1; m < 64; m <<= 1) y += __shfl_xor(y, m, 64);
    if (lane == 0) {
        float r = y + b3[0];
        if (*isf32) ((float*)out)[n] = r;
        else        ((bf16_t*)out)[n] = (bf16_t)r;
    }
}

// ---------------------------------------------------------------------------

extern "C" void kernel_launch(void* const* d_in, const int* in_sizes, int n_in,
                              void* d_out, int out_size, void* d_ws, size_t ws_size,
                              hipStream_t stream) {
    const int* ei = (const int*)d_in[1];

    char* ws = (char*)d_ws;
    size_t off = 0;
    auto alloc = [&](size_t bytes) {
        char* p = ws + off;
        off += (bytes + 255) & ~(size_t)255;
        return (void*)p;
    };
    float*  h_a   = (float*)alloc((size_t)NN * 32 * 4);
    float*  h_b   = (float*)alloc((size_t)NN * 32 * 4);
    float*  aggr  = (float*)alloc((size_t)NN * 32 * 4);
    float*  cnt   = (float*)alloc((size_t)NN * 4);
    int*    f32fl = (int*)alloc(256);
    int*    idxfl = (int*)alloc(256);
    int*    srcb  = (int*)alloc((size_t)EE * 4);
    int*    dstb  = (int*)alloc((size_t)EE * 4);
    bf16_t* k2t   = (bf16_t*)alloc(256 * 128 * 2);
    bf16_t* k3t   = (bf16_t*)alloc(1024 * 256 * 2);

    static const int fidx[N_FLT] = {0, 2, 3, 4, 5, 6, 7, 8, 9, 10, 11, 12, 13, 14, 15, 16};
    static const int fn[N_FLT]   = {NN * 6, EE * 6, 192, 32, 768, 128, 32768, 256,
                                    262144, 1024, 1024, 32, 4096, 128, 128, 1};
    int foffs[N_FLT];
    int tot = 0;
    for (int i = 0; i < N_FLT; ++i) { foffs[i] = tot; tot += fn[i]; }
    float* canon = (float*)alloc((size_t)tot * 4);
    const float* c_x    = canon + foffs[0];
    const float* c_ea   = canon + foffs[1];
    const float* c_fc1w = canon + foffs[2];
    const float* c_fc1b = canon + foffs[3];
    const float* c_k1w  = canon + foffs[4];
    const float* c_k1b  = canon + foffs[5];
    const float* c_k2w  = canon + foffs[6];
    const float* c_k2b  = canon + foffs[7];
    const float* c_k3w  = canon + foffs[8];
    const float* c_k3b  = canon + foffs[9];
    const float* c_rw   = canon + foffs[10];
    const float* c_cb   = canon + foffs[11];
    const float* c_fc2w = canon + foffs[12];
    const float* c_fc2b = canon + foffs[13];
    const float* c_fc3w = canon + foffs[14];
    const float* c_fc3b = canon + foffs[15];
    size_t fixed_end = off;

    const size_t per_tile = (size_t)128 * 128 * 2 + 128 * 256 * 2 + 128 * 1024 * 2;
    const int T_full = 64;
    size_t full_need = fixed_end
                     + (((size_t)T_full * 128 * 128 * 2 + 255) & ~(size_t)255)
                     + (((size_t)T_full * 128 * 256 * 2 + 255) & ~(size_t)255)
                     + (size_t)E_PAD * 1024 * 2;
    bool full = ws_size >= full_need;
    int T;
    if (full) {
        T = T_full;
    } else {
        size_t avail = ws_size > fixed_end + 4096 ? ws_size - fixed_end - 4096 : per_tile;
        long t = (long)(avail / per_tile);
        if (t > NTILES) t = NTILES;
        if (t < 1) t = 1;
        T = (int)t;
    }
    bf16_t* h1_c = (bf16_t*)alloc((size_t)T * 128 * 128 * 2);
    bf16_t* h2_c = (bf16_t*)alloc((size_t)T * 128 * 256 * 2);
    bf16_t* w_e  = (bf16_t*)alloc(full ? (size_t)E_PAD * 1024 * 2
                                       : (size_t)T * 128 * 1024 * 2);

    hipMemsetAsync(cnt, 0, (size_t)NN * 4, stream);
    hipMemsetAsync(f32fl, 0, 256, stream);
    hipMemsetAsync(idxfl, 0, 256, stream);

    detect_f32<<<32, 256, 0, stream>>>((const unsigned short*)d_in[2], f32fl);

    CvtArgs ca;
    for (int i = 0; i < N_FLT; ++i) {
        ca.src[i] = d_in[fidx[i]];
        ca.offs[i] = foffs[i];
        ca.n[i] = fn[i];
    }
    ca.dst = canon;
    {
        dim3 g((EE * 6 + 255) / 256, N_FLT);
        cvt_all<<<g, 256, 0, stream>>>(ca, f32fl);
    }

    detect_idx<<<16, 256, 0, stream>>>(ei, idxfl);
    repack_idx<<<(EE + 255) / 256, 256, 0, stream>>>(ei, idxfl, srcb, dstb);
    cnt_kernel<<<(EE + 255) / 256, 256, 0, stream>>>(dstb, cnt);
    transpose_bt<<<(128 * 256 + 255) / 256, 256, 0, stream>>>(c_k2w, k2t, 128, 256);
    transpose_bt<<<(256 * 1024 + 255) / 256, 256, 0, stream>>>(c_k3w, k3t, 256, 1024);
    h0_kernel<<<NN * 32 / 256, 256, 0, stream>>>(c_x, c_fc1w, c_fc1b, h_a);

    auto prep_chunk = [&](int tile0, int tiles, bf16_t* we_dst) {
        int rows = tiles * 128;
        h1_chunk<<<rows * 128 / 256, 256, 0, stream>>>(c_ea, c_k1w, c_k1b, h1_c, tile0 * 128);
        dim3 g2(tiles, 2);
        gemm_bt<<<g2, 256, 0, stream>>>(h1_c, k2t, c_k2b, h2_c, 128, 256, 1);
        dim3 g3(tiles, 8);
        gemm_bt<<<g3, 256, 0, stream>>>(h2_c, k3t, c_k3b, we_dst, 256, 1024, 0);
    };

    float* hc = h_a;
    float* hn = h_b;
    if (full) {
        for (int t0 = 0; t0 < NTILES; t0 += T) {
            int tl = (t0 + T <= NTILES) ? T : (NTILES - t0);
            prep_chunk(t0, tl, w_e + (size_t)t0 * 128 * 1024);
        }
        for (int d = 0; d < 4; ++d) {
            hipMemsetAsync(aggr, 0, (size_t)NN * 32 * 4, stream);
            matvec_scatter<<<(EE + 3) / 4, 256, 0, stream>>>(hc, w_e, srcb, dstb, aggr, 0, EE);
            node_update<<<NN * 32 / 256, 256, 0, stream>>>(hc, aggr, cnt, c_rw, c_cb, hn,
                                                           (d < 3) ? 1 : 0);
            float* tmp = hc; hc = hn; hn = tmp;
        }
    } else {
        for (int d = 0; d < 4; ++d) {
            hipMemsetAsync(aggr, 0, (size_t)NN * 32 * 4, stream);
            for (int t0 = 0; t0 < NTILES; t0 += T) {
                int tl = (t0 + T <= NTILES) ? T : (NTILES - t0);
                prep_chunk(t0, tl, w_e);
                int e0 = t0 * 128;
                int e1 = e0 + tl * 128; if (e1 > EE) e1 = EE;
                if (e1 > e0)
                    matvec_scatter<<<(e1 - e0 + 3) / 4, 256, 0, stream>>>(hc, w_e, srcb, dstb,
                                                                          aggr, e0, e1);
            }
            node_update<<<NN * 32 / 256, 256, 0, stream>>>(hc, aggr, cnt, c_rw, c_cb, hn,
                                                           (d < 3) ? 1 : 0);
            float* tmp = hc; hc = hn; hn = tmp;
        }
    }

    head_kernel<<<(NN + 3) / 4, 256, 0, stream>>>(hc, c_fc2w, c_fc2b, c_fc3w, c_fc3b,
                                                  d_out, f32fl);
}

// Round 6
// 712.579 us; speedup vs baseline: 2.0264x; 1.3962x over previous
//
#include <hip/hip_runtime.h>
#include <hip/hip_bf16.h>

#define NN 10000
#define EE 120000
#define E_PAD 120064   // 938 * 128
#define NTILES 938     // E_PAD / 128

typedef __bf16 bf16_t;
typedef __bf16 bf16x8 __attribute__((ext_vector_type(8)));
typedef float f32x4 __attribute__((ext_vector_type(4)));

static __device__ __forceinline__ int clampi(int v) {
    return v < 0 ? 0 : (v >= NN ? NN - 1 : v);
}

// ---- float dtype detection -------------------------------------------------
__global__ __launch_bounds__(256) void detect_f32(const unsigned short* __restrict__ ea_raw,
                                                  int* __restrict__ flag) {
    int t = blockIdx.x * 256 + threadIdx.x;   // [0, 8192) words, in-bounds either dtype
    if (ea_raw[t] & 0x8000) atomicOr(flag, 1);
}

// ---- batched convert of all 16 float tensors to canonical fp32 ------------
#define N_FLT 16
struct CvtArgs {
    const void* src[N_FLT];
    float* dst;
    int offs[N_FLT];
    int n[N_FLT];
};

__global__ __launch_bounds__(256) void cvt_all(CvtArgs a, const int* __restrict__ isf32) {
    int tensor = blockIdx.y;
    int i = blockIdx.x * 256 + threadIdx.x;
    if (i >= a.n[tensor]) return;
    float v;
    if (*isf32) v = ((const float*)a.src[tensor])[i];
    else        v = (float)((const bf16_t*)a.src[tensor])[i];
    if (!isfinite(v)) v = 0.f;
    a.dst[a.offs[tensor] + i] = v;
}

// ---- index dtype handling (int32 vs int64) ---------------------------------
__global__ __launch_bounds__(256) void detect_idx(const int* __restrict__ ei,
                                                  int* __restrict__ flag) {
    int t = blockIdx.x * 256 + threadIdx.x;          // [0, 4096)
    if (ei[2 * t + 1] != 0) atomicOr(flag, 1);       // any nonzero odd word -> int32
}

__global__ __launch_bounds__(256) void repack_idx(const int* __restrict__ ei,
                                                  const int* __restrict__ flag,
                                                  int* __restrict__ s,
                                                  int* __restrict__ d,
                                                  int* __restrict__ cnti) {
    int e = blockIdx.x * 256 + threadIdx.x;
    if (e >= EE) return;
    int sv, dv;
    if (*flag == 0) {   // int64
        sv = clampi(ei[2 * e]);
        dv = clampi(ei[2 * (EE + e)]);
    } else {            // int32
        sv = clampi(ei[e]);
        dv = clampi(ei[EE + e]);
    }
    s[e] = sv;
    d[e] = dv;
    atomicAdd(&cnti[dv], 1);
}

// single-block exclusive scan of cnti[NN] -> row_off[NN+1], pos copy
__global__ __launch_bounds__(256) void scan_kernel(const int* __restrict__ cnti,
                                                   int* __restrict__ row_off,
                                                   int* __restrict__ pos) {
    __shared__ int part[256];
    const int t = threadIdx.x;
    const int CH = (NN + 255) / 256;   // 40
    int s = 0;
    for (int i = 0; i < CH; ++i) {
        int idx = t * CH + i;
        if (idx < NN) s += cnti[idx];
    }
    part[t] = s;
    __syncthreads();
    for (int off = 1; off < 256; off <<= 1) {
        int tmp = (t >= off) ? part[t - off] : 0;
        __syncthreads();
        part[t] += tmp;
        __syncthreads();
    }
    int run = part[t] - s;   // exclusive prefix of this chunk
    for (int i = 0; i < CH; ++i) {
        int idx = t * CH + i;
        if (idx < NN) {
            row_off[idx] = run;
            pos[idx] = run;
            run += cnti[idx];
        }
    }
    if (t == 255) row_off[NN] = run;
}

// counting-sort scatter: order[] = edge ids grouped by dst
__global__ __launch_bounds__(256) void scatter_order(const int* __restrict__ dst,
                                                     int* __restrict__ pos,
                                                     int* __restrict__ order) {
    int e = blockIdx.x * 256 + threadIdx.x;
    if (e >= EE) return;
    int p = atomicAdd(&pos[dst[e]], 1);
    order[p] = e;
}

// ---- prep kernels (canonical fp32 in) --------------------------------------

// Bt[n][k] = B[k][n]  (plus optional output-permutation for k3: n' = o*32+i)
__global__ __launch_bounds__(256) void transpose_bt(const float* __restrict__ B,
                                                    bf16_t* __restrict__ Bt, int K, int N,
                                                    int permute) {
    int idx = blockIdx.x * 256 + threadIdx.x;   // idx = n*K + k
    if (idx >= K * N) return;
    int n = idx / K, k = idx - n * K;
    int c = permute ? (((n & 31) << 5) | (n >> 5)) : n;
    Bt[idx] = (bf16_t)B[k * N + c];
}

__global__ __launch_bounds__(256) void permute_bias(const float* __restrict__ b,
                                                    float* __restrict__ bp) {
    int n = blockIdx.x * 256 + threadIdx.x;   // [0,1024)
    bp[n] = b[((n & 31) << 5) | (n >> 5)];
}

// h0 = x @ fc1_w + fc1_b   (N x 32, fp32)
__global__ __launch_bounds__(256) void h0_kernel(const float* __restrict__ x,
                                                 const float* __restrict__ w,
                                                 const float* __restrict__ b,
                                                 float* __restrict__ h) {
    int gid = blockIdx.x * 256 + threadIdx.x;   // n*32 + o
    int n = gid >> 5, o = gid & 31;
    float acc = b[o];
#pragma unroll
    for (int j = 0; j < 6; ++j) acc += x[n * 6 + j] * w[j * 32 + o];
    h[gid] = acc;
}

// h1_c[r,:] = relu(edge_attr[e0+r,:] @ k1_w + k1_b)
__global__ __launch_bounds__(256) void h1_chunk(const float* __restrict__ ea,
                                                const float* __restrict__ k1w,
                                                const float* __restrict__ k1b,
                                                bf16_t* __restrict__ h1, int e0) {
    __shared__ float wk[6 * 128];
    __shared__ float bk[128];
    for (int i = threadIdx.x; i < 768; i += 256) wk[i] = k1w[i];
    if (threadIdx.x < 128) bk[threadIdx.x] = k1b[threadIdx.x];
    __syncthreads();
    int gid = blockIdx.x * 256 + threadIdx.x;   // r*128 + o
    int r = gid >> 7, o = gid & 127;
    int e = e0 + r;
    if (e >= EE) { h1[gid] = (bf16_t)0.f; return; }
    float acc = bk[o];
#pragma unroll
    for (int j = 0; j < 6; ++j) acc += ea[e * 6 + j] * wk[j * 128 + o];
    h1[gid] = (bf16_t)fmaxf(acc, 0.f);
}

// ---- MFMA GEMM:  C[M,Nd] = act(A[M,K] @ Bt[Nd,K]^T + bias) ----------------
__global__ __launch_bounds__(256) void gemm_bt(const bf16_t* __restrict__ A,
                                               const bf16_t* __restrict__ Bt,
                                               const float* __restrict__ bias,
                                               bf16_t* __restrict__ C,
                                               int K, int Nd, int relu) {
    __shared__ bf16_t As[128 * 32];
    __shared__ bf16_t Bs[128 * 32];
    const int t = threadIdx.x;
    const int lane = t & 63;
    const int wave = t >> 6;
    const int wm = wave >> 1, wn = wave & 1;
    const long m0 = (long)blockIdx.x * 128;
    const int n0 = blockIdx.y * 128;

    f32x4 acc[4][4];
#pragma unroll
    for (int i = 0; i < 4; ++i)
#pragma unroll
        for (int j = 0; j < 4; ++j) acc[i][j] = f32x4{0.f, 0.f, 0.f, 0.f};

    const int ar = t >> 2;
    const int ac = (t & 3) * 8;
    const bf16_t* gA0 = A + (m0 + ar) * (long)K + ac;
    const bf16_t* gA1 = A + (m0 + 64 + ar) * (long)K + ac;
    const bf16_t* gB0 = Bt + (long)(n0 + ar) * K + ac;
    const bf16_t* gB1 = Bt + (long)(n0 + 64 + ar) * K + ac;
    bf16_t* lA0 = &As[t * 8];
    bf16_t* lA1 = &As[2048 + t * 8];
    bf16_t* lB0 = &Bs[t * 8];
    bf16_t* lB1 = &Bs[2048 + t * 8];

    const int mrow = wm * 64 + (lane & 15);
    const int nrow = wn * 64 + (lane & 15);
    const int koff = (lane >> 4) * 8;

    for (int k0 = 0; k0 < K; k0 += 32) {
        bf16x8 va0 = *(const bf16x8*)(gA0 + k0);
        bf16x8 va1 = *(const bf16x8*)(gA1 + k0);
        bf16x8 vb0 = *(const bf16x8*)(gB0 + k0);
        bf16x8 vb1 = *(const bf16x8*)(gB1 + k0);
        __syncthreads();
        *(bf16x8*)lA0 = va0;
        *(bf16x8*)lA1 = va1;
        *(bf16x8*)lB0 = vb0;
        *(bf16x8*)lB1 = vb1;
        __syncthreads();

        bf16x8 af[4], bfr[4];
#pragma unroll
        for (int i = 0; i < 4; ++i) af[i] = *(const bf16x8*)&As[(mrow + i * 16) * 32 + koff];
#pragma unroll
        for (int j = 0; j < 4; ++j) bfr[j] = *(const bf16x8*)&Bs[(nrow + j * 16) * 32 + koff];
#pragma unroll
        for (int i = 0; i < 4; ++i)
#pragma unroll
            for (int j = 0; j < 4; ++j)
                acc[i][j] = __builtin_amdgcn_mfma_f32_16x16x32_bf16(af[i], bfr[j], acc[i][j], 0, 0, 0);
    }

    const int rbase = (lane >> 4) * 4;
    const int cidx = lane & 15;
#pragma unroll
    for (int i = 0; i < 4; ++i) {
#pragma unroll
        for (int j = 0; j < 4; ++j) {
            int col = n0 + wn * 64 + j * 16 + cidx;
            float bv = bias[col];
#pragma unroll
            for (int r = 0; r < 4; ++r) {
                long row = m0 + wm * 64 + i * 16 + rbase + r;
                float v = acc[i][j][r] + bv;
                if (relu) v = fmaxf(v, 0.f);
                C[row * Nd + col] = (bf16_t)v;
            }
        }
    }
}

// ---- CSR layer: one wave per node; no atomics ------------------------------
// wt layout: [E][out=32][in=32]. Lane l: o = l>>1, half = l&1 -> its 32B of
// wt[e] at element offset l*16 (coalesced 2 KB per wave load pair).
// h_out[n,o] = act( (sum_edges h[src][.]*wt[e][o][.]) / den + h[n]@rw + cb[o] )
__global__ __launch_bounds__(256) void gather_layer(const float* __restrict__ h,
                                                    const bf16_t* __restrict__ wt,
                                                    const int* __restrict__ src,
                                                    const int* __restrict__ order,
                                                    const int* __restrict__ row_off,
                                                    const float* __restrict__ rw,
                                                    const float* __restrict__ cb,
                                                    float* __restrict__ hout, int relu) {
    __shared__ float rws[1024];
    for (int i = threadIdx.x; i < 1024; i += 256) rws[i] = rw[i];
    __syncthreads();
    const int wv = threadIdx.x >> 6, lane = threadIdx.x & 63;
    const int n = blockIdx.x * 4 + wv;
    if (n >= NN) return;
    const int o = lane >> 1, half = lane & 1;

    const int b0 = row_off[n], b1 = row_off[n + 1];
    float acc0 = 0.f, acc1 = 0.f;
    for (int k = b0; k < b1; ++k) {
        int e = order[k];
        int s = src[e];
        const float4* hp = (const float4*)(h + (size_t)s * 32 + half * 16);
        float4 h0 = hp[0], h1v = hp[1], h2v = hp[2], h3v = hp[3];
        const bf16x8* wp = (const bf16x8*)(wt + (size_t)e * 1024 + lane * 16);
        bf16x8 w0 = wp[0], w1 = wp[1];
        acc0 += h0.x * (float)w0[0] + h0.y * (float)w0[1]
              + h0.z * (float)w0[2] + h0.w * (float)w0[3]
              + h1v.x * (float)w0[4] + h1v.y * (float)w0[5]
              + h1v.z * (float)w0[6] + h1v.w * (float)w0[7];
        acc1 += h2v.x * (float)w1[0] + h2v.y * (float)w1[1]
              + h2v.z * (float)w1[2] + h2v.w * (float)w1[3]
              + h3v.x * (float)w1[4] + h3v.y * (float)w1[5]
              + h3v.z * (float)w1[6] + h3v.w * (float)w1[7];
    }
    float acc = acc0 + acc1;

    // root partial: sum_j h[n][half*16+j] * rw[half*16+j][o]
    float rp = 0.f;
    const float4* hn = (const float4*)(h + (size_t)n * 32 + half * 16);
    float4 a = hn[0], b = hn[1], c = hn[2], dd = hn[3];
    const float* rwb = &rws[half * 16 * 32 + o];
    rp += a.x * rwb[0]   + a.y * rwb[32]  + a.z * rwb[64]  + a.w * rwb[96];
    rp += b.x * rwb[128] + b.y * rwb[160] + b.z * rwb[192] + b.w * rwb[224];
    rp += c.x * rwb[256] + c.y * rwb[288] + c.z * rwb[320] + c.w * rwb[352];
    rp += dd.x * rwb[384] + dd.y * rwb[416] + dd.z * rwb[448] + dd.w * rwb[480];

    acc += __shfl_xor(acc, 1, 64);
    rp  += __shfl_xor(rp, 1, 64);
    if (half == 0) {
        float den = fmaxf((float)(b1 - b0), 1.f);
        float v = acc / den + rp + cb[o];
        if (relu) v = fmaxf(v, 0.f);
        hout[(size_t)n * 32 + o] = v;
    }
}

// ---- fallback (ws too small for full w_e): per-edge wave + atomics ---------
__global__ __launch_bounds__(256) void edge_scatter(const float* __restrict__ h,
                                                    const bf16_t* __restrict__ wt,
                                                    const int* __restrict__ src,
                                                    const int* __restrict__ dst,
                                                    float* __restrict__ aggr,
                                                    int e0, int e1) {
    int wv = threadIdx.x >> 6, lane = threadIdx.x & 63;
    int e = e0 + blockIdx.x * 4 + wv;
    if (e >= e1) return;
    int s = src[e], d = dst[e];
    int o = lane >> 1, half = lane & 1;
    const float4* hp = (const float4*)(h + (size_t)s * 32 + half * 16);
    float4 h0 = hp[0], h1v = hp[1], h2v = hp[2], h3v = hp[3];
    const bf16x8* wp = (const bf16x8*)(wt + (size_t)(e - e0) * 1024 + lane * 16);
    bf16x8 w0 = wp[0], w1 = wp[1];
    float acc = h0.x * (float)w0[0] + h0.y * (float)w0[1]
              + h0.z * (float)w0[2] + h0.w * (float)w0[3]
              + h1v.x * (float)w0[4] + h1v.y * (float)w0[5]
              + h1v.z * (float)w0[6] + h1v.w * (float)w0[7]
              + h2v.x * (float)w1[0] + h2v.y * (float)w1[1]
              + h2v.z * (float)w1[2] + h2v.w * (float)w1[3]
              + h3v.x * (float)w1[4] + h3v.y * (float)w1[5]
              + h3v.z * (float)w1[6] + h3v.w * (float)w1[7];
    acc += __shfl_xor(acc, 1, 64);
    if (half == 0) atomicAdd(&aggr[(size_t)d * 32 + o], acc);
}

__global__ __launch_bounds__(256) void node_update(const float* __restrict__ hin,
                                                   const float* __restrict__ aggr,
                                                   const int* __restrict__ cnti,
                                                   const float* __restrict__ rw,
                                                   const float* __restrict__ cb,
                                                   float* __restrict__ hout, int relu) {
    __shared__ float rws[32 * 32];
    for (int i = threadIdx.x; i < 1024; i += 256) rws[i] = rw[i];
    __syncthreads();
    int gid = blockIdx.x * 256 + threadIdx.x;
    int n = gid >> 5, o = gid & 31;
    float den = fmaxf((float)cnti[n], 1.f);
    float acc = aggr[gid] / den + cb[o];
    const float* hrow = hin + (size_t)n * 32;
#pragma unroll
    for (int j = 0; j < 32; ++j) acc += hrow[j] * rws[j * 32 + o];
    if (relu) acc = fmaxf(acc, 0.f);
    hout[gid] = acc;
}

// out = relu(h @ fc2 + b2) @ fc3 + b3 ; one wave per node; out dtype per flag
__global__ __launch_bounds__(256) void head_kernel(const float* __restrict__ h,
                                                   const float* __restrict__ w2,
                                                   const float* __restrict__ b2,
                                                   const float* __restrict__ w3,
                                                   const float* __restrict__ b3,
                                                   void* __restrict__ out,
                                                   const int* __restrict__ isf32) {
    int wave = threadIdx.x >> 6, lane = threadIdx.x & 63;
    int n = blockIdx.x * 4 + wave;
    if (n >= NN) return;
    const float* hrow = h + (size_t)n * 32;
    float hr[32];
#pragma unroll
    for (int j = 0; j < 32; ++j) hr[j] = hrow[j];
    int o0 = lane * 2, o1 = lane * 2 + 1;
    float v0 = b2[o0], v1 = b2[o1];
#pragma unroll
    for (int j = 0; j < 32; ++j) {
        float hj = hr[j];
        v0 += hj * w2[j * 128 + o0];
        v1 += hj * w2[j * 128 + o1];
    }
    float y = fmaxf(v0, 0.f) * w3[o0] + fmaxf(v1, 0.f) * w3[o1];
#pragma unroll
    for (int m = 1; m < 64; m <<= 1) y += __shfl_xor(y, m, 64);
    if (lane == 0) {
        float r = y + b3[0];
        if (*isf32) ((float*)out)[n] = r;
        else        ((bf16_t*)out)[n] = (bf16_t)r;
    }
}

// ---------------------------------------------------------------------------

extern "C" void kernel_launch(void* const* d_in, const int* in_sizes, int n_in,
                              void* d_out, int out_size, void* d_ws, size_t ws_size,
                              hipStream_t stream) {
    const int* ei = (const int*)d_in[1];

    char* ws = (char*)d_ws;
    size_t off = 0;
    auto alloc = [&](size_t bytes) {
        char* p = ws + off;
        off += (bytes + 255) & ~(size_t)255;
        return (void*)p;
    };
    float*  h_a   = (float*)alloc((size_t)NN * 32 * 4);
    float*  h_b   = (float*)alloc((size_t)NN * 32 * 4);
    float*  aggr  = (float*)alloc((size_t)NN * 32 * 4);   // fallback only
    int*    cnti  = (int*)alloc((size_t)NN * 4);
    int*    rowo  = (int*)alloc((size_t)(NN + 1) * 4);
    int*    pos   = (int*)alloc((size_t)NN * 4);
    int*    f32fl = (int*)alloc(256);
    int*    idxfl = (int*)alloc(256);
    int*    srcb  = (int*)alloc((size_t)EE * 4);
    int*    dstb  = (int*)alloc((size_t)EE * 4);
    int*    order = (int*)alloc((size_t)EE * 4);
    bf16_t* k2t   = (bf16_t*)alloc(256 * 128 * 2);
    bf16_t* k3t   = (bf16_t*)alloc(1024 * 256 * 2);
    float*  k3bp  = (float*)alloc(1024 * 4);

    static const int fidx[N_FLT] = {0, 2, 3, 4, 5, 6, 7, 8, 9, 10, 11, 12, 13, 14, 15, 16};
    static const int fn[N_FLT]   = {NN * 6, EE * 6, 192, 32, 768, 128, 32768, 256,
                                    262144, 1024, 1024, 32, 4096, 128, 128, 1};
    int foffs[N_FLT];
    int tot = 0;
    for (int i = 0; i < N_FLT; ++i) { foffs[i] = tot; tot += fn[i]; }
    float* canon = (float*)alloc((size_t)tot * 4);
    const float* c_x    = canon + foffs[0];
    const float* c_ea   = canon + foffs[1];
    const float* c_fc1w = canon + foffs[2];
    const float* c_fc1b = canon + foffs[3];
    const float* c_k1w  = canon + foffs[4];
    const float* c_k1b  = canon + foffs[5];
    const float* c_k2w  = canon + foffs[6];
    const float* c_k2b  = canon + foffs[7];
    const float* c_k3w  = canon + foffs[8];
    const float* c_k3b  = canon + foffs[9];
    const float* c_rw   = canon + foffs[10];
    const float* c_cb   = canon + foffs[11];
    const float* c_fc2w = canon + foffs[12];
    const float* c_fc2b = canon + foffs[13];
    const float* c_fc3w = canon + foffs[14];
    const float* c_fc3b = canon + foffs[15];
    size_t fixed_end = off;

    // ---- mode selection on ws_size (constant per harness -> graph-safe) ----
    const size_t sz_we   = (size_t)E_PAD * 1024 * 2;           // 246 MB
    const size_t sz_h1f  = (size_t)E_PAD * 128 * 2;            // 30.7 MB
    const size_t sz_h2f  = (size_t)E_PAD * 256 * 2;            // 61.5 MB
    const int Tc = 64;                                          // chunk tiles
    const size_t sz_h1c  = (size_t)Tc * 128 * 128 * 2;
    const size_t sz_h2c  = (size_t)Tc * 128 * 256 * 2;
    size_t need2 = fixed_end + sz_we + sz_h1f + sz_h2f + 1024;  // single-pass prep
    size_t need1 = fixed_end + sz_we + sz_h1c + sz_h2c + 1024;  // chunked prep, full w_e
    int mode = (ws_size >= need2) ? 2 : (ws_size >= need1) ? 1 : 0;

    bf16_t *h1_b, *h2_b, *w_e;
    int T;
    if (mode == 2) {
        h1_b = (bf16_t*)alloc(sz_h1f);
        h2_b = (bf16_t*)alloc(sz_h2f);
        w_e  = (bf16_t*)alloc(sz_we);
        T = NTILES;
    } else if (mode == 1) {
        h1_b = (bf16_t*)alloc(sz_h1c);
        h2_b = (bf16_t*)alloc(sz_h2c);
        w_e  = (bf16_t*)alloc(sz_we);
        T = Tc;
    } else {
        size_t per_tile = (size_t)128 * 128 * 2 + 128 * 256 * 2 + 128 * 1024 * 2;
        size_t avail = ws_size > fixed_end + 4096 ? ws_size - fixed_end - 4096 : per_tile;
        long t = (long)(avail / per_tile);
        if (t > NTILES) t = NTILES;
        if (t < 1) t = 1;
        T = (int)t;
        h1_b = (bf16_t*)alloc((size_t)T * 128 * 128 * 2);
        h2_b = (bf16_t*)alloc((size_t)T * 128 * 256 * 2);
        w_e  = (bf16_t*)alloc((size_t)T * 128 * 1024 * 2);
    }

    hipMemsetAsync(cnti, 0, (size_t)NN * 4, stream);
    hipMemsetAsync(f32fl, 0, 256, stream);
    hipMemsetAsync(idxfl, 0, 256, stream);

    detect_f32<<<32, 256, 0, stream>>>((const unsigned short*)d_in[2], f32fl);

    CvtArgs ca;
    for (int i = 0; i < N_FLT; ++i) {
        ca.src[i] = d_in[fidx[i]];
        ca.offs[i] = foffs[i];
        ca.n[i] = fn[i];
    }
    ca.dst = canon;
    {
        dim3 g((EE * 6 + 255) / 256, N_FLT);
        cvt_all<<<g, 256, 0, stream>>>(ca, f32fl);
    }

    detect_idx<<<16, 256, 0, stream>>>(ei, idxfl);
    repack_idx<<<(EE + 255) / 256, 256, 0, stream>>>(ei, idxfl, srcb, dstb, cnti);
    scan_kernel<<<1, 256, 0, stream>>>(cnti, rowo, pos);
    scatter_order<<<(EE + 255) / 256, 256, 0, stream>>>(dstb, pos, order);

    transpose_bt<<<(128 * 256 + 255) / 256, 256, 0, stream>>>(c_k2w, k2t, 128, 256, 0);
    transpose_bt<<<(256 * 1024 + 255) / 256, 256, 0, stream>>>(c_k3w, k3t, 256, 1024, 1);
    permute_bias<<<4, 256, 0, stream>>>(c_k3b, k3bp);
    h0_kernel<<<NN * 32 / 256, 256, 0, stream>>>(c_x, c_fc1w, c_fc1b, h_a);

    auto prep_chunk = [&](int tile0, int tiles, bf16_t* we_dst) {
        int rows = tiles * 128;
        h1_chunk<<<rows * 128 / 256, 256, 0, stream>>>(c_ea, c_k1w, c_k1b, h1_b, tile0 * 128);
        dim3 g2(tiles, 2);
        gemm_bt<<<g2, 256, 0, stream>>>(h1_b, k2t, c_k2b, h2_b, 128, 256, 1);
        dim3 g3(tiles, 8);
        gemm_bt<<<g3, 256, 0, stream>>>(h2_b, k3t, k3bp, we_dst, 256, 1024, 0);
    };

    float* hc = h_a;
    float* hn = h_b;
    if (mode >= 1) {
        if (mode == 2) {
            prep_chunk(0, NTILES, w_e);
        } else {
            for (int t0 = 0; t0 < NTILES; t0 += T) {
                int tl = (t0 + T <= NTILES) ? T : (NTILES - t0);
                prep_chunk(t0, tl, w_e + (size_t)t0 * 128 * 1024);
            }
        }
        for (int d = 0; d < 4; ++d) {
            gather_layer<<<(NN + 3) / 4, 256, 0, stream>>>(hc, w_e, srcb, order, rowo,
                                                           c_rw, c_cb, hn, (d < 3) ? 1 : 0);
            float* tmp = hc; hc = hn; hn = tmp;
        }
    } else {
        for (int d = 0; d < 4; ++d) {
            hipMemsetAsync(aggr, 0, (size_t)NN * 32 * 4, stream);
            for (int t0 = 0; t0 < NTILES; t0 += T) {
                int tl = (t0 + T <= NTILES) ? T : (NTILES - t0);
                prep_chunk(t0, tl, w_e);
                int e0 = t0 * 128;
                int e1 = e0 + tl * 128; if (e1 > EE) e1 = EE;
                if (e1 > e0)
                    edge_scatter<<<(e1 - e0 + 3) / 4, 256, 0, stream>>>(hc, w_e, srcb, dstb,
                                                                        aggr, e0, e1);
            }
            node_update<<<NN * 32 / 256, 256, 0, stream>>>(hc, aggr, cnti, c_rw, c_cb, hn,
                                                           (d < 3) ? 1 : 0);
            float* tmp = hc; hc = hn; hn = tmp;
        }
    }

    head_kernel<<<(NN + 3) / 4, 256, 0, stream>>>(hc, c_fc2w, c_fc2b, c_fc3w, c_fc3b,
                                                  d_out, f32fl);
}

// Round 7
// 660.306 us; speedup vs baseline: 2.1869x; 1.0792x over previous
//
#include <hip/hip_runtime.h>
#include <hip/hip_bf16.h>

#define NN 10000
#define EE 120000
#define E_PAD 120064   // 938 * 128
#define NTILES 938     // E_PAD / 128

typedef __bf16 bf16_t;
typedef __bf16 bf16x8 __attribute__((ext_vector_type(8)));
typedef float f32x4 __attribute__((ext_vector_type(4)));

static __device__ __forceinline__ int clampi(int v) {
    return v < 0 ? 0 : (v >= NN ? NN - 1 : v);
}

// async global->LDS, 16B per lane (m97 structure; HW-verified learn_hip m97/m103)
static __device__ __forceinline__ void gld_lds16(const bf16_t* g, bf16_t* l) {
    __builtin_amdgcn_global_load_lds(
        (const __attribute__((address_space(1))) void*)g,
        (__attribute__((address_space(3))) void*)l,
        16, 0, 0);
}

// ---- float dtype detection -------------------------------------------------
__global__ __launch_bounds__(256) void detect_f32(const unsigned short* __restrict__ ea_raw,
                                                  int* __restrict__ flag) {
    int t = blockIdx.x * 256 + threadIdx.x;   // [0, 8192) words, in-bounds either dtype
    if (ea_raw[t] & 0x8000) atomicOr(flag, 1);
}

// ---- batched convert of all 16 float tensors to canonical fp32 ------------
#define N_FLT 16
struct CvtArgs {
    const void* src[N_FLT];
    float* dst;
    int offs[N_FLT];
    int n[N_FLT];
};

__global__ __launch_bounds__(256) void cvt_all(CvtArgs a, const int* __restrict__ isf32) {
    int tensor = blockIdx.y;
    int i = blockIdx.x * 256 + threadIdx.x;
    if (i >= a.n[tensor]) return;
    float v;
    if (*isf32) v = ((const float*)a.src[tensor])[i];
    else        v = (float)((const bf16_t*)a.src[tensor])[i];
    if (!isfinite(v)) v = 0.f;
    a.dst[a.offs[tensor] + i] = v;
}

// ---- index dtype handling (int32 vs int64) ---------------------------------
__global__ __launch_bounds__(256) void detect_idx(const int* __restrict__ ei,
                                                  int* __restrict__ flag) {
    int t = blockIdx.x * 256 + threadIdx.x;          // [0, 4096)
    if (ei[2 * t + 1] != 0) atomicOr(flag, 1);       // any nonzero odd word -> int32
}

__global__ __launch_bounds__(256) void repack_idx(const int* __restrict__ ei,
                                                  const int* __restrict__ flag,
                                                  int* __restrict__ s,
                                                  int* __restrict__ d,
                                                  int* __restrict__ cnti) {
    int e = blockIdx.x * 256 + threadIdx.x;
    if (e >= EE) return;
    int sv, dv;
    if (*flag == 0) {   // int64
        sv = clampi(ei[2 * e]);
        dv = clampi(ei[2 * (EE + e)]);
    } else {            // int32
        sv = clampi(ei[e]);
        dv = clampi(ei[EE + e]);
    }
    s[e] = sv;
    d[e] = dv;
    atomicAdd(&cnti[dv], 1);
}

// single-block exclusive scan of cnti[NN] -> row_off[NN+1], pos copy
__global__ __launch_bounds__(256) void scan_kernel(const int* __restrict__ cnti,
                                                   int* __restrict__ row_off,
                                                   int* __restrict__ pos) {
    __shared__ int part[256];
    const int t = threadIdx.x;
    const int CH = (NN + 255) / 256;   // 40
    int s = 0;
    for (int i = 0; i < CH; ++i) {
        int idx = t * CH + i;
        if (idx < NN) s += cnti[idx];
    }
    part[t] = s;
    __syncthreads();
    for (int off = 1; off < 256; off <<= 1) {
        int tmp = (t >= off) ? part[t - off] : 0;
        __syncthreads();
        part[t] += tmp;
        __syncthreads();
    }
    int run = part[t] - s;
    for (int i = 0; i < CH; ++i) {
        int idx = t * CH + i;
        if (idx < NN) {
            row_off[idx] = run;
            pos[idx] = run;
            run += cnti[idx];
        }
    }
    if (t == 255) row_off[NN] = run;
}

// rank[e] = sorted position of edge e (grouped by dst); src_s[p] = src of the
// edge at sorted position p. Pad rows map to themselves (positions >= EE).
__global__ __launch_bounds__(256) void scatter_rank(const int* __restrict__ dst,
                                                    const int* __restrict__ src,
                                                    int* __restrict__ pos,
                                                    int* __restrict__ rank,
                                                    int* __restrict__ src_s) {
    int e = blockIdx.x * 256 + threadIdx.x;
    if (e >= E_PAD) return;
    if (e >= EE) { rank[e] = e; return; }
    int p = atomicAdd(&pos[dst[e]], 1);
    rank[e] = p;
    src_s[p] = src[e];
}

// ---- prep kernels (canonical fp32 in) --------------------------------------

// Bt[n][k] = B[k][n]  (permute=1: output col n' = (n&31)*32 + (n>>5), i.e.
// k3 output reordered to [out][in] per edge)
__global__ __launch_bounds__(256) void transpose_bt(const float* __restrict__ B,
                                                    bf16_t* __restrict__ Bt, int K, int N,
                                                    int permute) {
    int idx = blockIdx.x * 256 + threadIdx.x;   // idx = n*K + k
    if (idx >= K * N) return;
    int n = idx / K, k = idx - n * K;
    int c = permute ? (((n & 31) << 5) | (n >> 5)) : n;
    Bt[idx] = (bf16_t)B[k * N + c];
}

__global__ __launch_bounds__(256) void permute_bias(const float* __restrict__ b,
                                                    float* __restrict__ bp) {
    int n = blockIdx.x * 256 + threadIdx.x;   // [0,1024)
    bp[n] = b[((n & 31) << 5) | (n >> 5)];
}

// h0 = x @ fc1_w + fc1_b   (N x 32, fp32)
__global__ __launch_bounds__(256) void h0_kernel(const float* __restrict__ x,
                                                 const float* __restrict__ w,
                                                 const float* __restrict__ b,
                                                 float* __restrict__ h) {
    int gid = blockIdx.x * 256 + threadIdx.x;
    int n = gid >> 5, o = gid & 31;
    float acc = b[o];
#pragma unroll
    for (int j = 0; j < 6; ++j) acc += x[n * 6 + j] * w[j * 32 + o];
    h[gid] = acc;
}

// h1_c[r,:] = relu(edge_attr[e0+r,:] @ k1_w + k1_b)
__global__ __launch_bounds__(256) void h1_chunk(const float* __restrict__ ea,
                                                const float* __restrict__ k1w,
                                                const float* __restrict__ k1b,
                                                bf16_t* __restrict__ h1, int e0) {
    __shared__ float wk[6 * 128];
    __shared__ float bk[128];
    for (int i = threadIdx.x; i < 768; i += 256) wk[i] = k1w[i];
    if (threadIdx.x < 128) bk[threadIdx.x] = k1b[threadIdx.x];
    __syncthreads();
    int gid = blockIdx.x * 256 + threadIdx.x;
    int r = gid >> 7, o = gid & 127;
    int e = e0 + r;
    if (e >= EE) { h1[gid] = (bf16_t)0.f; return; }
    float acc = bk[o];
#pragma unroll
    for (int j = 0; j < 6; ++j) acc += ea[e * 6 + j] * wk[j * 128 + o];
    h1[gid] = (bf16_t)fmaxf(acc, 0.f);
}

// ---- MFMA GEMM:  C[M,Nd] = act(A[M,K] @ Bt[Nd,K]^T + bias) ----------------
// m97 structure: global_load_lds width-16 staging, 2-barrier K-loop.
// perm=1: output row = rank[m_base + row] (dst-sorted w_e write).
__global__ __launch_bounds__(256) void gemm_bt(const bf16_t* __restrict__ A,
                                               const bf16_t* __restrict__ Bt,
                                               const float* __restrict__ bias,
                                               bf16_t* __restrict__ C,
                                               const int* __restrict__ rank,
                                               int K, int Nd, int relu,
                                               int perm, int m_base) {
    __shared__ bf16_t As[128 * 32];
    __shared__ bf16_t Bs[128 * 32];
    const int t = threadIdx.x;
    const int lane = t & 63;
    const int wave = t >> 6;
    const int wm = wave >> 1, wn = wave & 1;
    const long m0 = (long)blockIdx.x * 128;
    const int n0 = blockIdx.y * 128;

    f32x4 acc[4][4];
#pragma unroll
    for (int i = 0; i < 4; ++i)
#pragma unroll
        for (int j = 0; j < 4; ++j) acc[i][j] = f32x4{0.f, 0.f, 0.f, 0.f};

    const int ar = t >> 2;         // 0..63
    const int ac = (t & 3) * 8;    // k offset 0/8/16/24
    const bf16_t* gA0 = A + (m0 + ar) * (long)K + ac;
    const bf16_t* gA1 = A + (m0 + 64 + ar) * (long)K + ac;
    const bf16_t* gB0 = Bt + (long)(n0 + ar) * K + ac;
    const bf16_t* gB1 = Bt + (long)(n0 + 64 + ar) * K + ac;
    bf16_t* lA0 = &As[t * 8];         // wave base + lane*16B (contiguous)
    bf16_t* lA1 = &As[2048 + t * 8];
    bf16_t* lB0 = &Bs[t * 8];
    bf16_t* lB1 = &Bs[2048 + t * 8];

    const int mrow = wm * 64 + (lane & 15);
    const int nrow = wn * 64 + (lane & 15);
    const int koff = (lane >> 4) * 8;

    for (int k0 = 0; k0 < K; k0 += 32) {
        gld_lds16(gA0 + k0, lA0);
        gld_lds16(gA1 + k0, lA1);
        gld_lds16(gB0 + k0, lB0);
        gld_lds16(gB1 + k0, lB1);
        __syncthreads();   // vmcnt(0) drain + visibility

        bf16x8 af[4], bfr[4];
#pragma unroll
        for (int i = 0; i < 4; ++i) af[i] = *(const bf16x8*)&As[(mrow + i * 16) * 32 + koff];
#pragma unroll
        for (int j = 0; j < 4; ++j) bfr[j] = *(const bf16x8*)&Bs[(nrow + j * 16) * 32 + koff];
#pragma unroll
        for (int i = 0; i < 4; ++i)
#pragma unroll
            for (int j = 0; j < 4; ++j)
                acc[i][j] = __builtin_amdgcn_mfma_f32_16x16x32_bf16(af[i], bfr[j], acc[i][j], 0, 0, 0);
        __syncthreads();   // LDS reads done before next staging
    }

    // C/D layout: col = lane&15, row = (lane>>4)*4 + reg   [verified m89]
    const int rbase = (lane >> 4) * 4;
    const int cidx = lane & 15;
#pragma unroll
    for (int i = 0; i < 4; ++i) {
#pragma unroll
        for (int r = 0; r < 4; ++r) {
            long row = m0 + wm * 64 + i * 16 + rbase + r;
            long crow = perm ? (long)rank[m_base + row] : row;
#pragma unroll
            for (int j = 0; j < 4; ++j) {
                int col = n0 + wn * 64 + j * 16 + cidx;
                float v = acc[i][j][r] + bias[col];
                if (relu) v = fmaxf(v, 0.f);
                C[crow * Nd + col] = (bf16_t)v;
            }
        }
    }
}

// ---- CSR layer, dst-sorted streaming w_e; one wave per node; no atomics ----
// wt rows are sorted by dst: node n owns rows [row_off[n], row_off[n+1]).
// wt row layout [out=32][in=32]; lane l: o = l>>1, half = l&1.
__global__ __launch_bounds__(256) void gather_stream(const float* __restrict__ h,
                                                     const bf16_t* __restrict__ wt,
                                                     const int* __restrict__ src_s,
                                                     const int* __restrict__ row_off,
                                                     const float* __restrict__ rw,
                                                     const float* __restrict__ cb,
                                                     float* __restrict__ hout, int relu) {
    __shared__ float rws[1024];
    for (int i = threadIdx.x; i < 1024; i += 256) rws[i] = rw[i];
    __syncthreads();
    const int wv = threadIdx.x >> 6, lane = threadIdx.x & 63;
    const int n = blockIdx.x * 4 + wv;
    if (n >= NN) return;
    const int o = lane >> 1, half = lane & 1;

    const int b0 = row_off[n], b1 = row_off[n + 1];
    float acc = 0.f;
    if (b0 < b1) {
        int s = src_s[b0];
        const float4* hp = (const float4*)(h + (size_t)s * 32 + half * 16);
        float4 ha = hp[0], hb = hp[1], hcv = hp[2], hd = hp[3];
        const bf16x8* wp = (const bf16x8*)(wt + (size_t)b0 * 1024 + lane * 16);
        bf16x8 w0 = wp[0], w1 = wp[1];
        for (int k = b0; k + 1 < b1; ++k) {
            // prefetch next edge (addresses affine in k; src 1-level)
            int s2 = src_s[k + 1];
            const float4* hp2 = (const float4*)(h + (size_t)s2 * 32 + half * 16);
            float4 na = hp2[0], nb = hp2[1], nc = hp2[2], nd = hp2[3];
            const bf16x8* wp2 = (const bf16x8*)(wt + (size_t)(k + 1) * 1024 + lane * 16);
            bf16x8 nw0 = wp2[0], nw1 = wp2[1];
            acc += ha.x * (float)w0[0] + ha.y * (float)w0[1]
                 + ha.z * (float)w0[2] + ha.w * (float)w0[3]
                 + hb.x * (float)w0[4] + hb.y * (float)w0[5]
                 + hb.z * (float)w0[6] + hb.w * (float)w0[7]
                 + hcv.x * (float)w1[0] + hcv.y * (float)w1[1]
                 + hcv.z * (float)w1[2] + hcv.w * (float)w1[3]
                 + hd.x * (float)w1[4] + hd.y * (float)w1[5]
                 + hd.z * (float)w1[6] + hd.w * (float)w1[7];
            ha = na; hb = nb; hcv = nc; hd = nd; w0 = nw0; w1 = nw1;
        }
        acc += ha.x * (float)w0[0] + ha.y * (float)w0[1]
             + ha.z * (float)w0[2] + ha.w * (float)w0[3]
             + hb.x * (float)w0[4] + hb.y * (float)w0[5]
             + hb.z * (float)w0[6] + hb.w * (float)w0[7]
             + hcv.x * (float)w1[0] + hcv.y * (float)w1[1]
             + hcv.z * (float)w1[2] + hcv.w * (float)w1[3]
             + hd.x * (float)w1[4] + hd.y * (float)w1[5]
             + hd.z * (float)w1[6] + hd.w * (float)w1[7];
    }

    // root partial: sum_j h[n][half*16+j] * rw[half*16+j][o]
    float rp = 0.f;
    const float4* hn = (const float4*)(h + (size_t)n * 32 + half * 16);
    float4 a = hn[0], b = hn[1], c = hn[2], dd = hn[3];
    const float* rwb = &rws[half * 16 * 32 + o];
    rp += a.x * rwb[0]   + a.y * rwb[32]  + a.z * rwb[64]  + a.w * rwb[96];
    rp += b.x * rwb[128] + b.y * rwb[160] + b.z * rwb[192] + b.w * rwb[224];
    rp += c.x * rwb[256] + c.y * rwb[288] + c.z * rwb[320] + c.w * rwb[352];
    rp += dd.x * rwb[384] + dd.y * rwb[416] + dd.z * rwb[448] + dd.w * rwb[480];

    acc += __shfl_xor(acc, 1, 64);
    rp  += __shfl_xor(rp, 1, 64);
    if (half == 0) {
        float den = fmaxf((float)(b1 - b0), 1.f);
        float v = acc / den + rp + cb[o];
        if (relu) v = fmaxf(v, 0.f);
        hout[(size_t)n * 32 + o] = v;
    }
}

// ---- fallback (ws too small for full w_e): per-edge wave + atomics ---------
__global__ __launch_bounds__(256) void edge_scatter(const float* __restrict__ h,
                                                    const bf16_t* __restrict__ wt,
                                                    const int* __restrict__ src,
                                                    const int* __restrict__ dst,
                                                    float* __restrict__ aggr,
                                                    int e0, int e1) {
    int wv = threadIdx.x >> 6, lane = threadIdx.x & 63;
    int e = e0 + blockIdx.x * 4 + wv;
    if (e >= e1) return;
    int s = src[e], d = dst[e];
    int o = lane >> 1, half = lane & 1;
    const float4* hp = (const float4*)(h + (size_t)s * 32 + half * 16);
    float4 h0 = hp[0], h1v = hp[1], h2v = hp[2], h3v = hp[3];
    const bf16x8* wp = (const bf16x8*)(wt + (size_t)(e - e0) * 1024 + lane * 16);
    bf16x8 w0 = wp[0], w1 = wp[1];
    float acc = h0.x * (float)w0[0] + h0.y * (float)w0[1]
              + h0.z * (float)w0[2] + h0.w * (float)w0[3]
              + h1v.x * (float)w0[4] + h1v.y * (float)w0[5]
              + h1v.z * (float)w0[6] + h1v.w * (float)w0[7]
              + h2v.x * (float)w1[0] + h2v.y * (float)w1[1]
              + h2v.z * (float)w1[2] + h2v.w * (float)w1[3]
              + h3v.x * (float)w1[4] + h3v.y * (float)w1[5]
              + h3v.z * (float)w1[6] + h3v.w * (float)w1[7];
    acc += __shfl_xor(acc, 1, 64);
    if (half == 0) atomicAdd(&aggr[(size_t)d * 32 + o], acc);
}

__global__ __launch_bounds__(256) void node_update(const float* __restrict__ hin,
                                                   const float* __restrict__ aggr,
                                                   const int* __restrict__ cnti,
                                                   const float* __restrict__ rw,
                                                   const float* __restrict__ cb,
                                                   float* __restrict__ hout, int relu) {
    __shared__ float rws[32 * 32];
    for (int i = threadIdx.x; i < 1024; i += 256) rws[i] = rw[i];
    __syncthreads();
    int gid = blockIdx.x * 256 + threadIdx.x;
    int n = gid >> 5, o = gid & 31;
    float den = fmaxf((float)cnti[n], 1.f);
    float acc = aggr[gid] / den + cb[o];
    const float* hrow = hin + (size_t)n * 32;
#pragma unroll
    for (int j = 0; j < 32; ++j) acc += hrow[j] * rws[j * 32 + o];
    if (relu) acc = fmaxf(acc, 0.f);
    hout[gid] = acc;
}

// out = relu(h @ fc2 + b2) @ fc3 + b3 ; one wave per node; out dtype per flag
__global__ __launch_bounds__(256) void head_kernel(const float* __restrict__ h,
                                                   const float* __restrict__ w2,
                                                   const float* __restrict__ b2,
                                                   const float* __restrict__ w3,
                                                   const float* __restrict__ b3,
                                                   void* __restrict__ out,
                                                   const int* __restrict__ isf32) {
    int wave = threadIdx.x >> 6, lane = threadIdx.x & 63;
    int n = blockIdx.x * 4 + wave;
    if (n >= NN) return;
    const float* hrow = h + (size_t)n * 32;
    float hr[32];
#pragma unroll
    for (int j = 0; j < 32; ++j) hr[j] = hrow[j];
    int o0 = lane * 2, o1 = lane * 2 + 1;
    float v0 = b2[o0], v1 = b2[o1];
#pragma unroll
    for (int j = 0; j < 32; ++j) {
        float hj = hr[j];
        v0 += hj * w2[j * 128 + o0];
        v1 += hj * w2[j * 128 + o1];
    }
    float y = fmaxf(v0, 0.f) * w3[o0] + fmaxf(v1, 0.f) * w3[o1];
#pragma unroll
    for (int m = 1; m < 64; m <<= 1) y += __shfl_xor(y, m, 64);
    if (lane == 0) {
        float r = y + b3[0];
        if (*isf32) ((float*)out)[n] = r;
        else        ((bf16_t*)out)[n] = (bf16_t)r;
    }
}

// ---------------------------------------------------------------------------

extern "C" void kernel_launch(void* const* d_in, const int* in_sizes, int n_in,
                              void* d_out, int out_size, void* d_ws, size_t ws_size,
                              hipStream_t stream) {
    const int* ei = (const int*)d_in[1];

    char* ws = (char*)d_ws;
    size_t off = 0;
    auto alloc = [&](size_t bytes) {
        char* p = ws + off;
        off += (bytes + 255) & ~(size_t)255;
        return (void*)p;
    };
    float*  h_a   = (float*)alloc((size_t)NN * 32 * 4);
    float*  h_b   = (float*)alloc((size_t)NN * 32 * 4);
    int*    cnti  = (int*)alloc((size_t)NN * 4);
    int*    rowo  = (int*)alloc((size_t)(NN + 1) * 4);
    int*    pos   = (int*)alloc((size_t)NN * 4);
    int*    f32fl = (int*)alloc(256);
    int*    idxfl = (int*)alloc(256);
    int*    srcb  = (int*)alloc((size_t)EE * 4);
    int*    dstb  = (int*)alloc((size_t)EE * 4);
    int*    rankb = (int*)alloc((size_t)E_PAD * 4);
    int*    src_s = (int*)alloc((size_t)E_PAD * 4);
    bf16_t* k2t   = (bf16_t*)alloc(256 * 128 * 2);
    bf16_t* k3t   = (bf16_t*)alloc(1024 * 256 * 2);
    float*  k3bp  = (float*)alloc(1024 * 4);

    static const int fidx[N_FLT] = {0, 2, 3, 4, 5, 6, 7, 8, 9, 10, 11, 12, 13, 14, 15, 16};
    static const int fn[N_FLT]   = {NN * 6, EE * 6, 192, 32, 768, 128, 32768, 256,
                                    262144, 1024, 1024, 32, 4096, 128, 128, 1};
    int foffs[N_FLT];
    int tot = 0;
    for (int i = 0; i < N_FLT; ++i) { foffs[i] = tot; tot += fn[i]; }
    float* canon = (float*)alloc((size_t)tot * 4);
    const float* c_x    = canon + foffs[0];
    const float* c_ea   = canon + foffs[1];
    const float* c_fc1w = canon + foffs[2];
    const float* c_fc1b = canon + foffs[3];
    const float* c_k1w  = canon + foffs[4];
    const float* c_k1b  = canon + foffs[5];
    const float* c_k2w  = canon + foffs[6];
    const float* c_k2b  = canon + foffs[7];
    const float* c_k3w  = canon + foffs[8];
    const float* c_k3b  = canon + foffs[9];
    const float* c_rw   = canon + foffs[10];
    const float* c_cb   = canon + foffs[11];
    const float* c_fc2w = canon + foffs[12];
    const float* c_fc2b = canon + foffs[13];
    const float* c_fc3w = canon + foffs[14];
    const float* c_fc3b = canon + foffs[15];
    size_t fixed_end = off;

    // ---- mode selection on ws_size (constant per harness -> graph-safe) ----
    const size_t sz_we = (size_t)E_PAD * 1024 * 2;   // 246 MB
    auto chunk_need = [&](int Tq) {
        return fixed_end + sz_we
             + (((size_t)Tq * 128 * 128 * 2 + 255) & ~(size_t)255)
             + (((size_t)Tq * 128 * 256 * 2 + 255) & ~(size_t)255) + 1024;
    };
    int mode, T;
    if (ws_size >= chunk_need(NTILES))      { mode = 2; T = NTILES; }
    else if (ws_size >= chunk_need(128))    { mode = 1; T = 128; }
    else if (ws_size >= chunk_need(64))     { mode = 1; T = 64; }
    else                                    { mode = 0; T = 0; }

    bf16_t *h1_b, *h2_b, *w_e;
    float* aggr = nullptr;
    if (mode >= 1) {
        h1_b = (bf16_t*)alloc((size_t)T * 128 * 128 * 2);
        h2_b = (bf16_t*)alloc((size_t)T * 128 * 256 * 2);
        w_e  = (bf16_t*)alloc(sz_we);
    } else {
        aggr = (float*)alloc((size_t)NN * 32 * 4);
        size_t per_tile = (size_t)128 * 128 * 2 + 128 * 256 * 2 + 128 * 1024 * 2;
        size_t avail = ws_size > off + 4096 ? ws_size - off - 4096 : per_tile;
        long t = (long)(avail / per_tile);
        if (t > NTILES) t = NTILES;
        if (t < 1) t = 1;
        T = (int)t;
        h1_b = (bf16_t*)alloc((size_t)T * 128 * 128 * 2);
        h2_b = (bf16_t*)alloc((size_t)T * 128 * 256 * 2);
        w_e  = (bf16_t*)alloc((size_t)T * 128 * 1024 * 2);
    }

    hipMemsetAsync(cnti, 0, (size_t)NN * 4, stream);
    hipMemsetAsync(f32fl, 0, 256, stream);
    hipMemsetAsync(idxfl, 0, 256, stream);

    detect_f32<<<32, 256, 0, stream>>>((const unsigned short*)d_in[2], f32fl);

    CvtArgs ca;
    for (int i = 0; i < N_FLT; ++i) {
        ca.src[i] = d_in[fidx[i]];
        ca.offs[i] = foffs[i];
        ca.n[i] = fn[i];
    }
    ca.dst = canon;
    {
        dim3 g((EE * 6 + 255) / 256, N_FLT);
        cvt_all<<<g, 256, 0, stream>>>(ca, f32fl);
    }

    detect_idx<<<16, 256, 0, stream>>>(ei, idxfl);
    repack_idx<<<(EE + 255) / 256, 256, 0, stream>>>(ei, idxfl, srcb, dstb, cnti);
    scan_kernel<<<1, 256, 0, stream>>>(cnti, rowo, pos);
    scatter_rank<<<(E_PAD + 255) / 256, 256, 0, stream>>>(dstb, srcb, pos, rankb, src_s);

    transpose_bt<<<(128 * 256 + 255) / 256, 256, 0, stream>>>(c_k2w, k2t, 128, 256, 0);
    transpose_bt<<<(256 * 1024 + 255) / 256, 256, 0, stream>>>(c_k3w, k3t, 256, 1024, 1);
    permute_bias<<<4, 256, 0, stream>>>(c_k3b, k3bp);
    h0_kernel<<<NN * 32 / 256, 256, 0, stream>>>(c_x, c_fc1w, c_fc1b, h_a);

    // prep one chunk: h1 -> h2 -> w_e (k3 output dst-sorted when perm=1)
    auto prep_chunk = [&](int tile0, int tiles, bf16_t* c_dst, int perm) {
        int rows = tiles * 128;
        h1_chunk<<<rows * 128 / 256, 256, 0, stream>>>(c_ea, c_k1w, c_k1b, h1_b, tile0 * 128);
        dim3 g2(tiles, 2);
        gemm_bt<<<g2, 256, 0, stream>>>(h1_b, k2t, c_k2b, h2_b, rankb, 128, 256, 1, 0, 0);
        dim3 g3(tiles, 8);
        gemm_bt<<<g3, 256, 0, stream>>>(h2_b, k3t, k3bp, c_dst, rankb, 256, 1024, 0,
                                        perm, tile0 * 128);
    };

    float* hc = h_a;
    float* hn = h_b;
    if (mode >= 1) {
        for (int t0 = 0; t0 < NTILES; t0 += T) {
            int tl = (t0 + T <= NTILES) ? T : (NTILES - t0);
            prep_chunk(t0, tl, w_e, 1);   // C base global; rows via rank[]
        }
        for (int d = 0; d < 4; ++d) {
            gather_stream<<<(NN + 3) / 4, 256, 0, stream>>>(hc, w_e, src_s, rowo,
                                                            c_rw, c_cb, hn, (d < 3) ? 1 : 0);
            float* tmp = hc; hc = hn; hn = tmp;
        }
    } else {
        for (int d = 0; d < 4; ++d) {
            hipMemsetAsync(aggr, 0, (size_t)NN * 32 * 4, stream);
            for (int t0 = 0; t0 < NTILES; t0 += T) {
                int tl = (t0 + T <= NTILES) ? T : (NTILES - t0);
                prep_chunk(t0, tl, w_e, 0);
                int e0 = t0 * 128;
                int e1 = e0 + tl * 128; if (e1 > EE) e1 = EE;
                if (e1 > e0)
                    edge_scatter<<<(e1 - e0 + 3) / 4, 256, 0, stream>>>(hc, w_e, srcb, dstb,
                                                                        aggr, e0, e1);
            }
            node_update<<<NN * 32 / 256, 256, 0, stream>>>(hc, aggr, cnti, c_rw, c_cb, hn,
                                                           (d < 3) ? 1 : 0);
            float* tmp = hc; hc = hn; hn = tmp;
        }
    }

    head_kernel<<<(NN + 3) / 4, 256, 0, stream>>>(hc, c_fc2w, c_fc2b, c_fc3w, c_fc3b,
                                                  d_out, f32fl);
}